// Round 21
// baseline (310.785 us; speedup 1.0000x reference)
//
#include <hip/hip_runtime.h>
#include <stdint.h>

// 2-layer tanh RNN, fused, MFMA-RESIDENT state. B=4096, T=512, H=20.
// R21: kill the LDS broadcast (the measured ~600cyc/iter floor of R13-R20).
// One wave = 32 batches. h lives in bf16 B-fragments; W in A-fragments,
// compensated split W = W_hi + W_lo (both bf16) so weight rounding error
// ~2^-18; only h-storage error (~2e-3 steady) remains. Per step:
//   D = mfma(W_hi k0-15, B1) + mfma(W_hi k16-31, B2) + mfma(W_lo k0-15, B1)
// with C preloaded with bias + x-term. D->B relayout for the next step is
// 6 v_cvt_pk_bf16_f32 + 2 v_permlane32_swap (T12's verified 32x32 pattern)
// -- zero LDS, zero barriers. Grid = 128 single-wave blocks.
// Layouts (mfma_f32_32x32x16_bf16): A[r][k]: r=lane&31, k=8*(lane>>5)+i.
// B[k][c]: c=lane&31, k=8*(lane>>5)+i. D[r][c]: c=lane&31,
// r=(reg&3)+8*(reg>>2)+4*(lane>>5)  [C/D verified: learn_hip m74/m101].
// Pad rows/cols >=20 are exact zeros end-to-end (A rows zero, C zero,
// tanh(0)=0) so no masking is needed anywhere.

#define Bsz 4096
#define Tn  512
#define Hn  20
#define NB  32
#define NTHREADS 64

typedef __attribute__((ext_vector_type(8)))  short bf16x8;
typedef __attribute__((ext_vector_type(16))) float f32x16;

__device__ __forceinline__ float tanh_fast(float v) {
    float e = __expf(2.0f * v);
    return 1.0f - 2.0f * __builtin_amdgcn_rcpf(e + 1.0f);
}
__device__ __forceinline__ unsigned short f2bf(float f) {   // RN-even
    unsigned u = __float_as_uint(f);
    return (unsigned short)((u + 0x7FFFu + ((u >> 16) & 1u)) >> 16);
}
__device__ __forceinline__ float bf2f(unsigned short h) {
    return __uint_as_float(((unsigned)h) << 16);
}
__device__ __forceinline__ unsigned cvt_pk_bf16(float lo, float hi) {
    unsigned r;
    asm("v_cvt_pk_bf16_f32 %0, %1, %2" : "=v"(r) : "v"(lo), "v"(hi));
    return r;
}
__device__ __forceinline__ bf16x8 frag4(unsigned a, unsigned b,
                                        unsigned c, unsigned d) {
    union { unsigned u[4]; bf16x8 f; } x;
    x.u[0] = a; x.u[1] = b; x.u[2] = c; x.u[3] = d;
    return x.f;
}

#define MFMA(d, a, bfr) \
    d = __builtin_amdgcn_mfma_f32_32x32x16_bf16((a), (bfr), (d), 0, 0, 0)

// build hi+lo A fragments for rows r, k = KB + 8*half + [0..7]
#define MAKE_A(WPTR, KB, HIfrag, LOfrag) { \
    unsigned uh0=0,uh1=0,uh2=0,uh3=0, ul0=0,ul1=0,ul2=0,ul3=0; \
    unsigned uh[4], ul[4]; \
    _Pragma("unroll") \
    for (int p = 0; p < 4; ++p) { \
        int k0 = (KB) + 8*half + 2*p, k1 = k0 + 1; \
        float w0 = (r < Hn && k0 < Hn) ? (WPTR)[r*Hn + k0] : 0.f; \
        float w1 = (r < Hn && k1 < Hn) ? (WPTR)[r*Hn + k1] : 0.f; \
        unsigned short h0 = f2bf(w0), h1 = f2bf(w1); \
        uh[p] = (unsigned)h0 | ((unsigned)h1 << 16); \
        unsigned short l0 = f2bf(w0 - bf2f(h0)), l1 = f2bf(w1 - bf2f(h1)); \
        ul[p] = (unsigned)l0 | ((unsigned)l1 << 16); \
    } \
    uh0=uh[0]; uh1=uh[1]; uh2=uh[2]; uh3=uh[3]; \
    ul0=ul[0]; ul1=ul[1]; ul2=ul[2]; ul3=ul[3]; \
    HIfrag = frag4(uh0, uh1, uh2, uh3); \
    LOfrag = frag4(ul0, ul1, ul2, ul3); \
}

// build initial B fragment from f32 vector SRC (length Hn, zero-pad)
#define MAKE_B(SRC, KB, FR) { \
    unsigned ub[4]; \
    _Pragma("unroll") \
    for (int p = 0; p < 4; ++p) { \
        int k0 = (KB) + 8*half + 2*p, k1 = k0 + 1; \
        float v0 = (k0 < Hn) ? (SRC)[k0] : 0.f; \
        float v1 = (k1 < Hn) ? (SRC)[k1] : 0.f; \
        ub[p] = (unsigned)f2bf(v0) | ((unsigned)f2bf(v1) << 16); \
    } \
    FR = frag4(ub[0], ub[1], ub[2], ub[3]); \
}

#define TANH12(d, th) { \
    _Pragma("unroll") for (int p = 0; p < 12; ++p) th[p] = tanh_fast(d[p]); \
}

// D(tanh'd, f32x16 th) -> B fragments for the next mfma (T12 pattern)
#define REBUILD(th, B1f, B2f) { \
    unsigned q0 = cvt_pk_bf16(th[0],  th[1]); \
    unsigned q1 = cvt_pk_bf16(th[2],  th[3]); \
    unsigned q2 = cvt_pk_bf16(th[4],  th[5]); \
    unsigned q3 = cvt_pk_bf16(th[6],  th[7]); \
    unsigned q4 = cvt_pk_bf16(th[8],  th[9]); \
    unsigned q5 = cvt_pk_bf16(th[10], th[11]); \
    asm("v_permlane32_swap_b32 %0, %1" : "+v"(q0), "+v"(q2)); \
    asm("v_permlane32_swap_b32 %0, %1" : "+v"(q1), "+v"(q3)); \
    B1f = frag4(q0, q1, q2, q3); \
    B2f = frag4(q4, q5, 0u, 0u); \
}

__global__ __launch_bounds__(NTHREADS)
__attribute__((amdgpu_waves_per_eu(1, 1)))
void rnn2_mfma(const float* __restrict__ x,        // [B,T,1]
               const float* __restrict__ hidden,   // [2,B,H]
               const float* __restrict__ W_ih0,    // [H,1]
               const float* __restrict__ W_hh0,    // [H,H]
               const float* __restrict__ b_ih0,    // [H]
               const float* __restrict__ b_hh0,    // [H]
               const float* __restrict__ W_ih1,    // [H,H]
               const float* __restrict__ W_hh1,    // [H,H]
               const float* __restrict__ b_ih1,    // [H]
               const float* __restrict__ b_hh1,    // [H]
               const float* __restrict__ fc_w,     // [1,H]
               const float* __restrict__ fc_b,     // [1]
               float* __restrict__ out)            // [B] ++ [2,B,H] flat
{
    const int lane = threadIdx.x;
    const int c    = lane & 31;        // batch column
    const int half = lane >> 5;
    const int r    = c;                // A-fragment row
    const int bB   = blockIdx.x * NB;
    const int b    = bB + c;           // 4096 = 128*32: always valid

    // ---- A fragments: 3 matrices x {hi k0-15, hi k16-31, lo k0-15}
    bf16x8 A0h1, A0l1, A0h2, A0l2, A1h1, A1l1, A1h2, A1l2, A2h1, A2l1, A2h2, A2l2;
    MAKE_A(W_hh0, 0,  A0h1, A0l1)
    MAKE_A(W_hh0, 16, A0h2, A0l2)
    MAKE_A(W_ih1, 0,  A1h1, A1l1)
    MAKE_A(W_ih1, 16, A1h2, A1l2)
    MAKE_A(W_hh1, 0,  A2h1, A2l1)
    MAKE_A(W_hh1, 16, A2h2, A2l2)

    // ---- per-row constants in D layout (rows >= Hn -> 0)
    f32x16 wihv, b0v, b1v, fcwv;
    #pragma unroll
    for (int p = 0; p < 16; ++p) {
        const int row = (p & 3) + 8 * (p >> 2) + 4 * half;
        float wv = 0.f, bb0 = 0.f, bb1 = 0.f, fw = 0.f;
        if (row < Hn) {
            wv  = W_ih0[row];
            bb0 = b_ih0[row] + b_hh0[row];
            bb1 = b_ih1[row] + b_hh1[row];
            fw  = fc_w[row];
        }
        wihv[p] = wv; b0v[p] = bb0; b1v[p] = bb1; fcwv[p] = fw;
    }

    // ---- initial B fragments from f32 hidden state
    bf16x8 B01, B02, B11, B12;
    const float* h0src = hidden + (size_t)b * Hn;
    const float* h1src = hidden + (size_t)Bsz * Hn + (size_t)b * Hn;
    MAKE_B(h0src, 0, B01)  MAKE_B(h0src, 16, B02)
    MAKE_B(h1src, 0, B11)  MAKE_B(h1src, 16, B12)

    const float* xrow = x + (size_t)b * Tn;
    f32x16 th0, th1;

    // ---- peel t=0: h0[0] only
    {
        const float xt = xrow[0];
        f32x16 d0;
        #pragma unroll
        for (int p = 0; p < 16; ++p) d0[p] = fmaf(xt, wihv[p], b0v[p]);
        MFMA(d0, A0h1, B01); MFMA(d0, A0h2, B02); MFMA(d0, A0l1, B01);
        TANH12(d0, th0)
        REBUILD(th0, B01, B02)
    }

    // ---- main loop t=1..511: computes h0[t] and h1[t-1].
    // d1 consumes the OLD B01/B02 (h0[t-1]) + B11/B12 (h1[t-2]);
    // rebuilds happen after all mfmas of the iteration.
    #pragma unroll 1
    for (int t = 1; t < Tn; ++t) {
        const float xt = xrow[t];
        f32x16 d0, d1;
        #pragma unroll
        for (int p = 0; p < 16; ++p) {
            d0[p] = fmaf(xt, wihv[p], b0v[p]);
            d1[p] = b1v[p];
        }
        MFMA(d1, A1h1, B01); MFMA(d1, A1h2, B02); MFMA(d1, A1l1, B01);
        MFMA(d1, A2h1, B11); MFMA(d1, A2h2, B12); MFMA(d1, A2l1, B11);
        MFMA(d0, A0h1, B01); MFMA(d0, A0h2, B02); MFMA(d0, A0l1, B01);
        TANH12(d0, th0)
        REBUILD(th0, B01, B02)
        TANH12(d1, th1)
        REBUILD(th1, B11, B12)
    }

    // ---- epilogue: h1[511] from h0[511] (B01/B02) and h1[510] (B11/B12)
    {
        f32x16 d1;
        #pragma unroll
        for (int p = 0; p < 16; ++p) d1[p] = b1v[p];
        MFMA(d1, A1h1, B01); MFMA(d1, A1h2, B02); MFMA(d1, A1l1, B01);
        MFMA(d1, A2h1, B11); MFMA(d1, A2h2, B12); MFMA(d1, A2l1, B11);
        TANH12(d1, th1)
    }

    // ---- outputs: th0 = h0[511], th1 = h1[511] (f32, pre-pack)
    #pragma unroll
    for (int p = 0; p < 12; ++p) {
        const int row = (p & 3) + 8 * (p >> 2) + 4 * half;
        if (row < Hn) {
            out[Bsz + (size_t)b * Hn + row]                    = th0[p];
            out[Bsz + (size_t)Bsz * Hn + (size_t)b * Hn + row] = th1[p];
        }
    }
    float pp = 0.f;
    #pragma unroll
    for (int p = 0; p < 12; ++p) pp = fmaf(fcwv[p], th1[p], pp);
    pp += __shfl_xor(pp, 32);
    if (half == 0) out[b] = pp + fc_b[0];
}

extern "C" void kernel_launch(void* const* d_in, const int* in_sizes, int n_in,
                              void* d_out, int out_size, void* d_ws, size_t ws_size,
                              hipStream_t stream) {
    const float* x      = (const float*)d_in[0];
    const float* hidden = (const float*)d_in[1];
    const float* W_ih0  = (const float*)d_in[2];
    const float* W_hh0  = (const float*)d_in[3];
    const float* b_ih0  = (const float*)d_in[4];
    const float* b_hh0  = (const float*)d_in[5];
    const float* W_ih1  = (const float*)d_in[6];
    const float* W_hh1  = (const float*)d_in[7];
    const float* b_ih1  = (const float*)d_in[8];
    const float* b_hh1  = (const float*)d_in[9];
    const float* fc_w   = (const float*)d_in[10];
    const float* fc_b   = (const float*)d_in[11];

    rnn2_mfma<<<Bsz / NB, NTHREADS, 0, stream>>>(
        x, hidden, W_ih0, W_hh0, b_ih0, b_hh0,
        W_ih1, W_hh1, b_ih1, b_hh1, fc_w, fc_b, (float*)d_out);
}

// Round 22
// 163.785 us; speedup vs baseline: 1.8975x; 1.8975x over previous
//
#include <hip/hip_runtime.h>

// 2-layer tanh RNN, fused, f32, single-wave blocks, no barriers.
// R22: TWO INDEPENDENT BATCH-GROUP PIPELINES PER WAVE (A=3 batches,
// B=3 batches). Source order per iter: [A dots->tanh->write->reads]
// [B dots->tanh->write->reads]; A's LDS read latency (~150cyc) is covered
// by B's compute section and vice versa --真 independent work, unlike
// R17's same-pipeline reordering. Weights shared across groups (60 VGPR);
// h-state carried in regs (READ_INTO after each write). 683 blocks.
// B=4096, T=512, H=20. waves_per_eu(1,2): RA budget 256 (~180 live).

#define Bsz 4096
#define Tn  512
#define Hn  20
#define GPW 6                  // batches per wave (2 groups x 3)
#define XPAD 520
#define NTHREADS 64

typedef float v2 __attribute__((ext_vector_type(2)));

__device__ __forceinline__ float tanh_fast(float v) {
    // tanh(v) = 1 - 2/(exp(2v)+1); v_exp_f32 + v_rcp_f32.
    float e = __expf(2.0f * v);
    return 1.0f - 2.0f * __builtin_amdgcn_rcpf(e + 1.0f);
}

// packed 20-dot: 10 v_pk_fma_f32, two chains
#define DOT20P(acc, accb, W, H) do { \
    acc  = __builtin_elementwise_fma(W##0, H##0, acc);  \
    accb = __builtin_elementwise_fma(W##1, H##1, accb); \
    acc  = __builtin_elementwise_fma(W##2, H##2, acc);  \
    accb = __builtin_elementwise_fma(W##3, H##3, accb); \
    acc  = __builtin_elementwise_fma(W##4, H##4, acc);  \
    accb = __builtin_elementwise_fma(W##5, H##5, accb); \
    acc  = __builtin_elementwise_fma(W##6, H##6, acc);  \
    accb = __builtin_elementwise_fma(W##7, H##7, accb); \
    acc  = __builtin_elementwise_fma(W##8, H##8, acc);  \
    accb = __builtin_elementwise_fma(W##9, H##9, accb); \
} while (0)

#define LOAD_ROWP(W, ptr) \
    v2 W##0, W##1, W##2, W##3, W##4, W##5, W##6, W##7, W##8, W##9; \
    { const float4* _p = (const float4*)(ptr); \
      float4 _t; \
      _t = _p[0]; W##0 = (v2){_t.x, _t.y}; W##1 = (v2){_t.z, _t.w}; \
      _t = _p[1]; W##2 = (v2){_t.x, _t.y}; W##3 = (v2){_t.z, _t.w}; \
      _t = _p[2]; W##4 = (v2){_t.x, _t.y}; W##5 = (v2){_t.z, _t.w}; \
      _t = _p[3]; W##6 = (v2){_t.x, _t.y}; W##7 = (v2){_t.z, _t.w}; \
      _t = _p[4]; W##8 = (v2){_t.x, _t.y}; W##9 = (v2){_t.z, _t.w}; }

#define DECL_H(H) v2 H##0, H##1, H##2, H##3, H##4, H##5, H##6, H##7, H##8, H##9;

#define READ_INTO(H, base) do { \
    const float4 _a = *(const float4*)((base) + 0);  \
    const float4 _b = *(const float4*)((base) + 4);  \
    const float4 _c = *(const float4*)((base) + 8);  \
    const float4 _d = *(const float4*)((base) + 12); \
    const float4 _e = *(const float4*)((base) + 16); \
    H##0 = (v2){_a.x, _a.y}; H##1 = (v2){_a.z, _a.w}; \
    H##2 = (v2){_b.x, _b.y}; H##3 = (v2){_b.z, _b.w}; \
    H##4 = (v2){_c.x, _c.y}; H##5 = (v2){_c.z, _c.w}; \
    H##6 = (v2){_d.x, _d.y}; H##7 = (v2){_d.z, _d.w}; \
    H##8 = (v2){_e.x, _e.y}; H##9 = (v2){_e.z, _e.w}; \
} while (0)

__global__ __launch_bounds__(NTHREADS)
__attribute__((amdgpu_waves_per_eu(1, 2)))
void rnn2_fused(const float* __restrict__ x,        // [B,T,1]
                const float* __restrict__ hidden,   // [2,B,H]
                const float* __restrict__ W_ih0,    // [H,1]
                const float* __restrict__ W_hh0,    // [H,H]
                const float* __restrict__ b_ih0,    // [H]
                const float* __restrict__ b_hh0,    // [H]
                const float* __restrict__ W_ih1,    // [H,H]
                const float* __restrict__ W_hh1,    // [H,H]
                const float* __restrict__ b_ih1,    // [H]
                const float* __restrict__ b_hh1,    // [H]
                const float* __restrict__ fc_w,     // [1,H]
                const float* __restrict__ fc_b,     // [1]
                float* __restrict__ out)            // [B] ++ [2,B,H] flat
{
    const int tid = threadIdx.x;
    int g = tid / Hn;                  // 0..3
    int j = tid - g * Hn;
    const bool lane_ok = (tid < 3 * Hn);
    if (!lane_ok) { g = 2; j = tid - 60; }   // dup lanes: benign

    const int  bA   = blockIdx.x * GPW + g;        // group A batch
    const int  bB   = bA + 3;                      // group B batch
    const bool okA  = lane_ok && (bA < Bsz);
    const bool okB  = lane_ok && (bB < Bsz);
    const int  blA  = (bA < Bsz) ? bA : (Bsz - 1);
    const int  blB  = (bB < Bsz) ? bB : (Bsz - 1);

    __shared__ float xs[GPW][XPAD];    // 12.5 KB
    __shared__ float hs[2][GPW][Hn];   // [layer][slot][j]; A=0..2, B=3..5

    // ---- shared weight rows (both groups use the same rows)
    LOAD_ROWP(w0, W_hh0 + j * Hn)
    LOAD_ROWP(w1, W_ih1 + j * Hn)
    LOAD_ROWP(w2, W_hh1 + j * Hn)
    const float wih0  = W_ih0[j];
    const float bias0 = b_ih0[j] + b_hh0[j];
    const float bias1 = b_ih1[j] + b_hh1[j];

    // ---- stage ALL x (coalesced float4; clamped batch rows)
    {
        const int bBase = blockIdx.x * GPW;
        #pragma unroll
        for (int r = 0; r < (GPW * Tn) / (NTHREADS * 4); ++r) {  // 12 rounds
            const int c  = (r * NTHREADS + tid) * 4;
            const int gg = c >> 9;
            const int t  = c & (Tn - 1);
            const int bb = (bBase + gg < Bsz) ? (bBase + gg) : (Bsz - 1);
            float4 v = *(const float4*)(x + (long)bb * Tn + t);
            *(float4*)&xs[gg][t] = v;
        }
    }

    // ---- init state mailboxes + pull into carry registers
    hs[0][g][j]     = hidden[blA * Hn + j];
    hs[1][g][j]     = hidden[(long)Bsz * Hn + blA * Hn + j];
    hs[0][g + 3][j] = hidden[blB * Hn + j];
    hs[1][g + 3][j] = hidden[(long)Bsz * Hn + blB * Hn + j];
    // single-wave in-order DS pipe: reads below see these writes

    DECL_H(hA0) DECL_H(hA1) DECL_H(hB0) DECL_H(hB1)
    READ_INTO(hA0, &hs[0][g][0]);          // h0[-1] A
    READ_INTO(hA1, &hs[1][g][0]);          // h1[-1] A
    READ_INTO(hB0, &hs[0][g + 3][0]);      // h0[-1] B
    READ_INTO(hB1, &hs[1][g + 3][0]);      // h1[-1] B

    // ---- peel i=0: h0[0] per group
    {
        v2 a  = (v2){fmaf(xs[g][0], wih0, bias0), 0.f};
        v2 ab = (v2){0.f, 0.f};
        DOT20P(a, ab, w0, hA0);
        const v2 s = a + ab;
        hs[0][g][j] = tanh_fast(s.x + s.y);
        READ_INTO(hA0, &hs[0][g][0]);      // hA0 = h0[0]
        v2 c  = (v2){fmaf(xs[g + 3][0], wih0, bias0), 0.f};
        v2 cb = (v2){0.f, 0.f};
        DOT20P(c, cb, w0, hB0);
        const v2 t = c + cb;
        hs[0][g + 3][j] = tanh_fast(t.x + t.y);
        READ_INTO(hB0, &hs[0][g + 3][0]);  // hB0 = h0[0]
    }
    float xtA = xs[g][1];
    float xtB = xs[g + 3][1];

    float n0A = 0.f, n0B = 0.f;
    // ---- main loop i=1..511. Entry: hX0=h0[i-1], hX1=h1[i-2] (regs).
    // A's reads are covered by B's compute; B's by next iter's A compute.
    #pragma unroll 1
    for (int i = 1; i < Tn; ++i) {
        const int tn2 = (i + 1 < Tn) ? (i + 1) : (Tn - 1);

        // ======== group A ========
        {
            v2 a0  = (v2){fmaf(xtA, wih0, bias0), 0.f};
            v2 a0b = (v2){0.f, 0.f};
            v2 a1  = (v2){bias1, 0.f};
            v2 a1b = (v2){0.f, 0.f};
            v2 a2  = (v2){0.f, 0.f};
            v2 a2b = (v2){0.f, 0.f};
            DOT20P(a0, a0b, w0, hA0);
            DOT20P(a1, a1b, w1, hA0);
            DOT20P(a2, a2b, w2, hA1);
            const v2 s0 = a0 + a0b;
            const v2 s1 = (a1 + a1b) + (a2 + a2b);
            const float n0 = tanh_fast(s0.x + s0.y);
            const float n1 = tanh_fast(s1.x + s1.y);
            n0A = n0;
            hs[0][g][j] = n0;                  // h0[i]
            hs[1][g][j] = n1;                  // h1[i-1]
            READ_INTO(hA0, &hs[0][g][0]);      // issue now; B covers latency
            READ_INTO(hA1, &hs[1][g][0]);
            xtA = xs[g][tn2];
        }
        // ======== group B ========
        {
            v2 a0  = (v2){fmaf(xtB, wih0, bias0), 0.f};
            v2 a0b = (v2){0.f, 0.f};
            v2 a1  = (v2){bias1, 0.f};
            v2 a1b = (v2){0.f, 0.f};
            v2 a2  = (v2){0.f, 0.f};
            v2 a2b = (v2){0.f, 0.f};
            DOT20P(a0, a0b, w0, hB0);
            DOT20P(a1, a1b, w1, hB0);
            DOT20P(a2, a2b, w2, hB1);
            const v2 s0 = a0 + a0b;
            const v2 s1 = (a1 + a1b) + (a2 + a2b);
            const float n0 = tanh_fast(s0.x + s0.y);
            const float n1 = tanh_fast(s1.x + s1.y);
            n0B = n0;
            hs[0][g + 3][j] = n0;
            hs[1][g + 3][j] = n1;
            READ_INTO(hB0, &hs[0][g + 3][0]);  // next-iter A covers latency
            READ_INTO(hB1, &hs[1][g + 3][0]);
            xtB = xs[g + 3][tn2];
        }
    }

    // ---- epilogue: h1[511] per group (hX0=h0[511], hX1=h1[510])
    float n1A, n1B;
    {
        v2 a1  = (v2){bias1, 0.f};
        v2 a1b = (v2){0.f, 0.f};
        v2 a2  = (v2){0.f, 0.f};
        v2 a2b = (v2){0.f, 0.f};
        DOT20P(a1, a1b, w1, hA0);
        DOT20P(a2, a2b, w2, hA1);
        const v2 s = (a1 + a1b) + (a2 + a2b);
        n1A = tanh_fast(s.x + s.y);
        hs[1][g][j] = n1A;
    }
    {
        v2 a1  = (v2){bias1, 0.f};
        v2 a1b = (v2){0.f, 0.f};
        v2 a2  = (v2){0.f, 0.f};
        v2 a2b = (v2){0.f, 0.f};
        DOT20P(a1, a1b, w1, hB0);
        DOT20P(a2, a2b, w2, hB1);
        const v2 s = (a1 + a1b) + (a2 + a2b);
        n1B = tanh_fast(s.x + s.y);
        hs[1][g + 3][j] = n1B;
    }

    // ---- outputs
    if (okA) {
        out[Bsz + (long)bA * Hn + j]                  = n0A;   // h0[511]
        out[Bsz + (long)Bsz * Hn + (long)bA * Hn + j] = n1A;   // h1[511]
    }
    if (okB) {
        out[Bsz + (long)bB * Hn + j]                  = n0B;
        out[Bsz + (long)Bsz * Hn + (long)bB * Hn + j] = n1B;
    }
    if (j == 0) {                      // fc heads: one lane per batch
        LOAD_ROWP(fw, fc_w)
        if (okA) {
            DECL_H(hv)
            READ_INTO(hv, &hs[1][g][0]);
            v2 aA = (v2){fc_b[0], 0.f};
            v2 aB = (v2){0.f, 0.f};
            DOT20P(aA, aB, fw, hv);
            const v2 s = aA + aB;
            out[bA] = s.x + s.y;
        }
        if (okB) {
            DECL_H(hv)
            READ_INTO(hv, &hs[1][g + 3][0]);
            v2 aA = (v2){fc_b[0], 0.f};
            v2 aB = (v2){0.f, 0.f};
            DOT20P(aA, aB, fw, hv);
            const v2 s = aA + aB;
            out[bB] = s.x + s.y;
        }
    }
}

extern "C" void kernel_launch(void* const* d_in, const int* in_sizes, int n_in,
                              void* d_out, int out_size, void* d_ws, size_t ws_size,
                              hipStream_t stream) {
    const float* x      = (const float*)d_in[0];
    const float* hidden = (const float*)d_in[1];
    const float* W_ih0  = (const float*)d_in[2];
    const float* W_hh0  = (const float*)d_in[3];
    const float* b_ih0  = (const float*)d_in[4];
    const float* b_hh0  = (const float*)d_in[5];
    const float* W_ih1  = (const float*)d_in[6];
    const float* W_hh1  = (const float*)d_in[7];
    const float* b_ih1  = (const float*)d_in[8];
    const float* b_hh1  = (const float*)d_in[9];
    const float* fc_w   = (const float*)d_in[10];
    const float* fc_b   = (const float*)d_in[11];

    const int nblocks = (Bsz + GPW - 1) / GPW;   // 683
    rnn2_fused<<<nblocks, NTHREADS, 0, stream>>>(
        x, hidden, W_ih0, W_hh0, b_ih0, b_hh0,
        W_ih1, W_hh1, b_ih1, b_hh1, fc_w, fc_b, (float*)d_out);
}